// Round 1
// baseline (390.277 us; speedup 1.0000x reference)
//
#include <hip/hip_runtime.h>
#include <hip/hip_bf16.h>

typedef unsigned short u16;
typedef unsigned int   u32;
typedef __attribute__((ext_vector_type(8))) short bf16x8;
typedef __attribute__((ext_vector_type(4))) float f32x4;
typedef __attribute__((ext_vector_type(4))) float f4v;
typedef __attribute__((ext_vector_type(4))) u16  u16x4;

#define BB 2
#define SS 2048
#define DD 1024
#define HH 16
#define HSZ 64
#define ATT_SCALE 0.125f  // 1/sqrt(64)

__device__ __forceinline__ u16 f2bf(float f) {
  union { float f; u32 u; } c; c.f = f;
  u32 u = c.u + 0x7fffu + ((c.u >> 16) & 1u);
  return (u16)(u >> 16);
}

__device__ __forceinline__ void gload_lds16(const void* g, void* l) {
  __builtin_amdgcn_global_load_lds(
      (const __attribute__((address_space(1))) u32*)g,
      (__attribute__((address_space(3))) u32*)l, 16, 0, 0);
}

// ---------------------------------------------------------------- conversion
__global__ void cvt_bf16_kernel(const float* __restrict__ s0, const float* __restrict__ s1,
                                const float* __restrict__ s2, const float* __restrict__ s3,
                                u16* __restrict__ d0, u16* __restrict__ d1,
                                u16* __restrict__ d2, u16* __restrict__ d3, int n4) {
  const int z = blockIdx.y;
  const float* s = (z == 0) ? s0 : (z == 1) ? s1 : (z == 2) ? s2 : s3;
  u16* d = (z == 0) ? d0 : (z == 1) ? d1 : (z == 2) ? d2 : d3;
  int i = blockIdx.x * blockDim.x + threadIdx.x;
  int stride = gridDim.x * blockDim.x;
  for (int k = i; k < n4; k += stride) {
    f4v v = ((const f4v*)s)[k];
    u16x4 o;
    o[0] = f2bf(v[0]); o[1] = f2bf(v[1]); o[2] = f2bf(v[2]); o[3] = f2bf(v[3]);
    ((u16x4*)d)[k] = o;
  }
}

// ---------------------------------------------------------------- GEMM  C = A * W^T + bias
// A: (M,K) bf16 row-major.  W: (N,K) bf16 row-major (nn.Linear weight).  128x128 tile, 4 waves.
template<int OUT_F32>
__global__ __launch_bounds__(256, 2) void gemm_bt_kernel(
    const u16* __restrict__ A, const u16* __restrict__ W,
    const float* __restrict__ bias, void* __restrict__ Cp,
    int M, int N, int K) {
  __shared__ u16 As[128 * 32];
  __shared__ u16 Bs[128 * 32];
  const int t = threadIdx.x;
  const int lane = t & 63, w = t >> 6;
  const int wr = w >> 1, wc = w & 1;
  const int l15 = lane & 15, l4 = lane >> 4;
  const int m0 = blockIdx.x * 128, n0 = blockIdx.y * 128;

  f32x4 acc[4][4];
#pragma unroll
  for (int m = 0; m < 4; ++m)
#pragma unroll
    for (int n = 0; n < 4; ++n) acc[m][n] = (f32x4)(0.0f);

  const int kc = (t & 3) * 8;
  const int nk = K >> 5;
  for (int kt = 0; kt < nk; ++kt) {
    __syncthreads();
#pragma unroll
    for (int i = 0; i < 2; ++i) {
      int row = (i * 256 + t) >> 2;
      gload_lds16(A + (size_t)(m0 + row) * K + kt * 32 + kc, &As[i * 2048 + w * 512]);
      gload_lds16(W + (size_t)(n0 + row) * K + kt * 32 + kc, &Bs[i * 2048 + w * 512]);
    }
    __syncthreads();
    bf16x8 af[4], bfr[4];
#pragma unroll
    for (int m = 0; m < 4; ++m) af[m] = *(const bf16x8*)&As[(wr * 64 + m * 16 + l15) * 32 + l4 * 8];
#pragma unroll
    for (int n = 0; n < 4; ++n) bfr[n] = *(const bf16x8*)&Bs[(wc * 64 + n * 16 + l15) * 32 + l4 * 8];
#pragma unroll
    for (int m = 0; m < 4; ++m)
#pragma unroll
      for (int n = 0; n < 4; ++n)
        acc[m][n] = __builtin_amdgcn_mfma_f32_16x16x32_bf16(af[m], bfr[n], acc[m][n], 0, 0, 0);
  }

  float bv[4];
#pragma unroll
  for (int n = 0; n < 4; ++n) bv[n] = bias[n0 + wc * 64 + n * 16 + l15];
#pragma unroll
  for (int m = 0; m < 4; ++m) {
#pragma unroll
    for (int j = 0; j < 4; ++j) {
      int r = m0 + wr * 64 + m * 16 + l4 * 4 + j;
#pragma unroll
      for (int n = 0; n < 4; ++n) {
        int cc = n0 + wc * 64 + n * 16 + l15;
        float v = acc[m][n][j] + bv[n];
        if (OUT_F32) ((float*)Cp)[(size_t)r * N + cc] = v;
        else         ((u16*)Cp)[(size_t)r * N + cc] = f2bf(v);
      }
    }
  }
}

// ---------------------------------------------------------------- causal flash attention
// grid: (S/128, B*H). 4 waves, each owns 32 q-rows. KBLK=64.
// Writes context in the reference's head-major reshape layout.
__global__ __launch_bounds__(256, 2) void attn_kernel(
    const u16* __restrict__ Qb, const u16* __restrict__ Kb,
    const u16* __restrict__ Vb, u16* __restrict__ Xb) {
  __shared__ u16 Kl[64 * 72];
  __shared__ u16 Vt[64 * 72];
  __shared__ u16 Pl[128 * 72];

  const int qt = blockIdx.x;
  const int bh = blockIdx.y;
  const int b = bh >> 4, h = bh & 15;
  const int q0 = qt * 128;
  const int t = threadIdx.x;
  const int lane = t & 63, w = t >> 6;
  const int l15 = lane & 15, l4 = lane >> 4;

  // Q fragments (rows w*32 + mf*16 + l15, dims kf*32 + l4*8 .. +7), hoisted
  bf16x8 aq[2][2];
#pragma unroll
  for (int mf = 0; mf < 2; ++mf)
#pragma unroll
    for (int kf = 0; kf < 2; ++kf)
      aq[mf][kf] = *(const bf16x8*)&Qb[((size_t)b * SS + q0 + w * 32 + mf * 16 + l15) * DD +
                                       h * 64 + kf * 32 + l4 * 8];

  f32x4 acc[2][4];
  float mrun[2][4], lrun[2][4];
#pragma unroll
  for (int mf = 0; mf < 2; ++mf)
#pragma unroll
    for (int x = 0; x < 4; ++x) {
      acc[mf][x] = (f32x4)(0.0f);
      mrun[mf][x] = -3.0e38f;
      lrun[mf][x] = 0.0f;
    }

  const int nkt = 2 * qt + 2;
  for (int kt = 0; kt < nkt; ++kt) {
    const int k0 = kt * 64;
    __syncthreads();
    // stage K (row-major, stride 72) and V transposed (Vt[d][key], stride 72)
#pragma unroll
    for (int i = 0; i < 2; ++i) {
      int c = i * 256 + t;
      int r = c >> 3, d0 = (c & 7) * 8;
      size_t goff = ((size_t)b * SS + k0 + r) * DD + h * 64 + d0;
      bf16x8 kv = *(const bf16x8*)&Kb[goff];
      *(bf16x8*)&Kl[r * 72 + d0] = kv;
      bf16x8 vv = *(const bf16x8*)&Vb[goff];
#pragma unroll
      for (int jj = 0; jj < 8; ++jj) {
        int dd = (jj + (t & 7)) & 7;  // rotate write order: spread banks
        Vt[(d0 + dd) * 72 + r] = (u16)vv[dd];
      }
    }
    __syncthreads();

    // S = Q K^T   (C layout: q-row = l4*4+j (+mf*16), key = l15 (+nf*16))
    f32x4 s[2][4];
#pragma unroll
    for (int mf = 0; mf < 2; ++mf)
#pragma unroll
      for (int nf = 0; nf < 4; ++nf) s[mf][nf] = (f32x4)(0.0f);
#pragma unroll
    for (int nf = 0; nf < 4; ++nf)
#pragma unroll
      for (int kf = 0; kf < 2; ++kf) {
        bf16x8 bk = *(const bf16x8*)&Kl[(nf * 16 + l15) * 72 + kf * 32 + l4 * 8];
#pragma unroll
        for (int mf = 0; mf < 2; ++mf)
          s[mf][nf] = __builtin_amdgcn_mfma_f32_16x16x32_bf16(aq[mf][kf], bk, s[mf][nf], 0, 0, 0);
      }

    const bool need_mask = (k0 + 63 > q0 + w * 32);
#pragma unroll
    for (int mf = 0; mf < 2; ++mf)
#pragma unroll
      for (int nf = 0; nf < 4; ++nf)
#pragma unroll
        for (int j = 0; j < 4; ++j) {
          float v = s[mf][nf][j] * ATT_SCALE;
          if (need_mask) {
            int key = k0 + nf * 16 + l15;
            int qrow = q0 + w * 32 + mf * 16 + l4 * 4 + j;
            if (key > qrow) v = -1.0e9f;
          }
          s[mf][nf][j] = v;
        }

    // online softmax update (row reduce across the 16-lane col group)
#pragma unroll
    for (int mf = 0; mf < 2; ++mf)
#pragma unroll
      for (int j = 0; j < 4; ++j) {
        float v = fmaxf(fmaxf(s[mf][0][j], s[mf][1][j]), fmaxf(s[mf][2][j], s[mf][3][j]));
        v = fmaxf(v, __shfl_xor(v, 1));
        v = fmaxf(v, __shfl_xor(v, 2));
        v = fmaxf(v, __shfl_xor(v, 4));
        v = fmaxf(v, __shfl_xor(v, 8));
        float mnew = fmaxf(mrun[mf][j], v);
        float sc = __expf(mrun[mf][j] - mnew);
        mrun[mf][j] = mnew;
        float sum = 0.0f;
#pragma unroll
        for (int nf = 0; nf < 4; ++nf) {
          float p = __expf(s[mf][nf][j] - mnew);
          s[mf][nf][j] = p;
          sum += p;
        }
        sum += __shfl_xor(sum, 1);
        sum += __shfl_xor(sum, 2);
        sum += __shfl_xor(sum, 4);
        sum += __shfl_xor(sum, 8);
        lrun[mf][j] = lrun[mf][j] * sc + sum;
#pragma unroll
        for (int nd = 0; nd < 4; ++nd) acc[mf][nd][j] *= sc;
      }

    // P -> LDS (per-wave region, within-wave in-order LDS => no barrier needed)
#pragma unroll
    for (int mf = 0; mf < 2; ++mf)
#pragma unroll
      for (int nf = 0; nf < 4; ++nf)
#pragma unroll
        for (int j = 0; j < 4; ++j)
          Pl[(w * 32 + mf * 16 + l4 * 4 + j) * 72 + nf * 16 + l15] = f2bf(s[mf][nf][j]);

    // PV: acc += P(32x64) * V(64x64)
    bf16x8 ap[2][2];
#pragma unroll
    for (int mf = 0; mf < 2; ++mf)
#pragma unroll
      for (int kf = 0; kf < 2; ++kf)
        ap[mf][kf] = *(const bf16x8*)&Pl[(w * 32 + mf * 16 + l15) * 72 + kf * 32 + l4 * 8];
#pragma unroll
    for (int nd = 0; nd < 4; ++nd)
#pragma unroll
      for (int kf = 0; kf < 2; ++kf) {
        bf16x8 bvf = *(const bf16x8*)&Vt[(nd * 16 + l15) * 72 + kf * 32 + l4 * 8];
#pragma unroll
        for (int mf = 0; mf < 2; ++mf)
          acc[mf][nd] = __builtin_amdgcn_mfma_f32_16x16x32_bf16(ap[mf][kf], bvf, acc[mf][nd], 0, 0, 0);
      }
  }

  // epilogue: write context in reference reshape layout: flat = h*S*64 + s*64 + d
#pragma unroll
  for (int mf = 0; mf < 2; ++mf)
#pragma unroll
    for (int j = 0; j < 4; ++j) {
      float inv = 1.0f / lrun[mf][j];
      int srow = q0 + w * 32 + mf * 16 + l4 * 4 + j;
      size_t base = (size_t)b * SS * DD + (size_t)h * SS * 64 + (size_t)srow * 64;
#pragma unroll
      for (int nd = 0; nd < 4; ++nd)
        Xb[base + nd * 16 + l15] = f2bf(acc[mf][nd][j] * inv);
    }
}

// ---------------------------------------------------------------- launch
extern "C" void kernel_launch(void* const* d_in, const int* in_sizes, int n_in,
                              void* d_out, int out_size, void* d_ws, size_t ws_size,
                              hipStream_t stream) {
  const float* q_in = (const float*)d_in[0];
  const float* k_in = (const float*)d_in[1];
  const float* v_in = (const float*)d_in[2];
  const float* Wq = (const float*)d_in[3];
  const float* bq = (const float*)d_in[4];
  const float* Wk = (const float*)d_in[5];
  const float* bk = (const float*)d_in[6];
  const float* Wv = (const float*)d_in[7];
  const float* bv = (const float*)d_in[8];
  const float* Wo = (const float*)d_in[9];
  const float* bo = (const float*)d_in[10];

  char* ws = (char*)d_ws;
  const size_t SZ_IN = (size_t)BB * SS * DD * 2;  // 8 MiB (bf16 activation)
  const size_t SZ_W = (size_t)DD * DD * 2;        // 2 MiB (bf16 weight)
  u16* qb  = (u16*)(ws);
  u16* kb  = (u16*)(ws + SZ_IN);
  u16* vb  = (u16*)(ws + 2 * SZ_IN);
  u16* wqb = (u16*)(ws + 3 * SZ_IN);
  u16* wkb = (u16*)(ws + 3 * SZ_IN + SZ_W);
  u16* wvb = (u16*)(ws + 3 * SZ_IN + 2 * SZ_W);
  u16* wob = (u16*)(ws + 3 * SZ_IN + 3 * SZ_W);
  u16* Qb  = (u16*)(ws + 3 * SZ_IN + 4 * SZ_W);
  u16* Kb  = (u16*)(ws + 4 * SZ_IN + 4 * SZ_W);
  u16* Vb  = (u16*)(ws + 5 * SZ_IN + 4 * SZ_W);
  u16* Xb  = (u16*)(ws + 6 * SZ_IN + 4 * SZ_W);

  // fp32 -> bf16
  cvt_bf16_kernel<<<dim3(2048, 3), 256, 0, stream>>>(q_in, k_in, v_in, nullptr,
                                                     qb, kb, vb, nullptr, (BB * SS * DD) / 4);
  cvt_bf16_kernel<<<dim3(1024, 4), 256, 0, stream>>>(Wq, Wk, Wv, Wo,
                                                     wqb, wkb, wvb, wob, (DD * DD) / 4);

  // Q/K/V projections
  gemm_bt_kernel<0><<<dim3(32, 8), 256, 0, stream>>>(qb, wqb, bq, Qb, BB * SS, DD, DD);
  gemm_bt_kernel<0><<<dim3(32, 8), 256, 0, stream>>>(kb, wkb, bk, Kb, BB * SS, DD, DD);
  gemm_bt_kernel<0><<<dim3(32, 8), 256, 0, stream>>>(vb, wvb, bv, Vb, BB * SS, DD, DD);

  // causal attention
  attn_kernel<<<dim3(SS / 128, BB * HH), 256, 0, stream>>>(Qb, Kb, Vb, Xb);

  // output projection (fp32 out)
  gemm_bt_kernel<1><<<dim3(32, 8), 256, 0, stream>>>(Xb, wob, bo, d_out, BB * SS, DD, DD);
}

// Round 3
// 319.650 us; speedup vs baseline: 1.2210x; 1.2210x over previous
//
#include <hip/hip_runtime.h>
#include <hip/hip_bf16.h>

typedef unsigned short u16;
typedef unsigned int   u32;
typedef __attribute__((ext_vector_type(8))) short bf16x8;
typedef __attribute__((ext_vector_type(4))) float f32x4;
typedef __attribute__((ext_vector_type(4))) float f4v;
typedef __attribute__((ext_vector_type(4))) u16  u16x4;

#define BB 2
#define SS 2048
#define DD 1024
#define HH 16
#define ATT_SCALE 0.125f  // 1/sqrt(64)

__device__ __forceinline__ u16 f2bf(float f) {
  union { float f; u32 u; } c; c.f = f;
  u32 u = c.u + 0x7fffu + ((c.u >> 16) & 1u);
  return (u16)(u >> 16);
}

__device__ __forceinline__ void gload_lds16(const void* g, void* l) {
  __builtin_amdgcn_global_load_lds(
      (const __attribute__((address_space(1))) u32*)g,
      (__attribute__((address_space(3))) u32*)l, 16, 0, 0);
}

// ---------------------------------------------------------------- conversion
__global__ void cvt_bf16_kernel(const float* __restrict__ s0, const float* __restrict__ s1,
                                const float* __restrict__ s2, const float* __restrict__ s3,
                                u16* __restrict__ d0, u16* __restrict__ d1,
                                u16* __restrict__ d2, u16* __restrict__ d3, int n4) {
  const int z = blockIdx.y;
  const float* s = (z == 0) ? s0 : (z == 1) ? s1 : (z == 2) ? s2 : s3;
  u16* d = (z == 0) ? d0 : (z == 1) ? d1 : (z == 2) ? d2 : d3;
  int i = blockIdx.x * blockDim.x + threadIdx.x;
  int stride = gridDim.x * blockDim.x;
  for (int k = i; k < n4; k += stride) {
    f4v v = ((const f4v*)s)[k];
    u16x4 o;
    o[0] = f2bf(v[0]); o[1] = f2bf(v[1]); o[2] = f2bf(v[2]); o[3] = f2bf(v[3]);
    ((u16x4*)d)[k] = o;
  }
}

// ---------------------------------------------------------------- GEMM  C = A * W^T + bias
// 128x64 tile, 4 waves (2x2), BK=32. z-batched over up to 3 independent GEMMs.
template<int OUT_F32>
__global__ __launch_bounds__(256, 4) void gemm_bt_kernel(
    const u16* __restrict__ A0, const u16* __restrict__ A1, const u16* __restrict__ A2,
    const u16* __restrict__ W0, const u16* __restrict__ W1, const u16* __restrict__ W2,
    const float* __restrict__ b0, const float* __restrict__ b1, const float* __restrict__ b2,
    void* __restrict__ C0, void* __restrict__ C1, void* __restrict__ C2,
    int M, int N, int K) {
  const int z = blockIdx.z;
  const u16* A = (z == 0) ? A0 : (z == 1) ? A1 : A2;
  const u16* W = (z == 0) ? W0 : (z == 1) ? W1 : W2;
  const float* bias = (z == 0) ? b0 : (z == 1) ? b1 : b2;
  void* Cp = (z == 0) ? C0 : (z == 1) ? C1 : C2;

  __shared__ u16 As[128 * 32];
  __shared__ u16 Bs[64 * 32];
  const int t = threadIdx.x;
  const int lane = t & 63, w = t >> 6;
  const int wr = w >> 1, wc = w & 1;
  const int l15 = lane & 15, l4 = lane >> 4;
  const int m0 = blockIdx.x * 128, n0 = blockIdx.y * 64;

  f32x4 acc[4][2];
#pragma unroll
  for (int m = 0; m < 4; ++m)
#pragma unroll
    for (int n = 0; n < 2; ++n) acc[m][n] = (f32x4)(0.0f);

  const int kc = (t & 3) * 8;
  const int nk = K >> 5;
  for (int kt = 0; kt < nk; ++kt) {
    __syncthreads();
#pragma unroll
    for (int i = 0; i < 2; ++i) {
      int row = (i * 256 + t) >> 2;
      gload_lds16(A + (size_t)(m0 + row) * K + kt * 32 + kc, &As[i * 2048 + w * 512]);
    }
    {
      int row = t >> 2;
      gload_lds16(W + (size_t)(n0 + row) * K + kt * 32 + kc, &Bs[w * 512]);
    }
    __syncthreads();
    bf16x8 af[4], bfr[2];
#pragma unroll
    for (int m = 0; m < 4; ++m) af[m] = *(const bf16x8*)&As[(wr * 64 + m * 16 + l15) * 32 + l4 * 8];
#pragma unroll
    for (int n = 0; n < 2; ++n) bfr[n] = *(const bf16x8*)&Bs[(wc * 32 + n * 16 + l15) * 32 + l4 * 8];
#pragma unroll
    for (int m = 0; m < 4; ++m)
#pragma unroll
      for (int n = 0; n < 2; ++n)
        acc[m][n] = __builtin_amdgcn_mfma_f32_16x16x32_bf16(af[m], bfr[n], acc[m][n], 0, 0, 0);
  }

  float bv[2];
#pragma unroll
  for (int n = 0; n < 2; ++n) bv[n] = bias[n0 + wc * 32 + n * 16 + l15];
#pragma unroll
  for (int m = 0; m < 4; ++m) {
#pragma unroll
    for (int j = 0; j < 4; ++j) {
      int r = m0 + wr * 64 + m * 16 + l4 * 4 + j;
#pragma unroll
      for (int n = 0; n < 2; ++n) {
        int cc = n0 + wc * 32 + n * 16 + l15;
        float v = acc[m][n][j] + bv[n];
        if (OUT_F32) ((float*)Cp)[(size_t)r * N + cc] = v;
        else         ((u16*)Cp)[(size_t)r * N + cc] = f2bf(v);
      }
    }
  }
}

// ---------------------------------------------------------------- causal flash attention
// grid: (S/64, B*H), qt reversed (big blocks first). 4 waves x 16 q-rows. KBLK=64.
// Register ping-pong prefetch of next K/V tile (T14 async-stage split).
__global__ __launch_bounds__(256, 3) void attn_kernel(
    const u16* __restrict__ Qb, const u16* __restrict__ Kb,
    const u16* __restrict__ Vb, u16* __restrict__ Xb) {
  __shared__ u16 Kl[64 * 72];
  __shared__ u16 Vt[64 * 72];  // Vt[d][r], r XOR-swizzled by (d>>3)
  __shared__ u16 Pl[64 * 72];

  const int qt = (int)gridDim.x - 1 - (int)blockIdx.x;  // biggest first
  const int bh = blockIdx.y;
  const int b = bh >> 4, h = bh & 15;
  const int q0 = qt * 64;
  const int t = threadIdx.x;
  const int lane = t & 63, w = t >> 6;
  const int l15 = lane & 15, l4 = lane >> 4;

  // Q fragments: rows q0 + w*16 + l15, dims kf*32 + l4*8
  bf16x8 aq[2];
#pragma unroll
  for (int kf = 0; kf < 2; ++kf)
    aq[kf] = *(const bf16x8*)&Qb[((size_t)b * SS + q0 + w * 16 + l15) * DD +
                                 h * 64 + kf * 32 + l4 * 8];

  f32x4 acc[4];
  float mrun[4], lrun[4];
#pragma unroll
  for (int x = 0; x < 4; ++x) {
    acc[x] = (f32x4)(0.0f);
    mrun[x] = -3.0e38f;
    lrun[x] = 0.0f;
  }

  auto prefetch = [&](int kt, bf16x8* kr, bf16x8* vr) {
#pragma unroll
    for (int i = 0; i < 2; ++i) {
      int c = i * 256 + t;
      size_t goff = ((size_t)b * SS + kt * 64 + (c >> 3)) * DD + h * 64 + (c & 7) * 8;
      kr[i] = *(const bf16x8*)&Kb[goff];
      vr[i] = *(const bf16x8*)&Vb[goff];
    }
  };

  auto stage_write = [&](const bf16x8* kr, const bf16x8* vr) {
#pragma unroll
    for (int i = 0; i < 2; ++i) {
      int c = i * 256 + t;
      int r = c >> 3, d0 = (c & 7) * 8;
      *(bf16x8*)&Kl[r * 72 + d0] = kr[i];
      int rsw = r ^ ((c & 7) << 3);  // bank swizzle, matches read-side XOR
#pragma unroll
      for (int jj = 0; jj < 8; ++jj)
        Vt[(d0 + jj) * 72 + rsw] = (u16)vr[i][jj];
    }
  };

  auto compute = [&](int kt) {
    const int k0 = kt * 64;
    f32x4 s[4];
#pragma unroll
    for (int nf = 0; nf < 4; ++nf) s[nf] = (f32x4)(0.0f);
#pragma unroll
    for (int nf = 0; nf < 4; ++nf)
#pragma unroll
      for (int kf = 0; kf < 2; ++kf) {
        bf16x8 bk = *(const bf16x8*)&Kl[(nf * 16 + l15) * 72 + kf * 32 + l4 * 8];
        s[nf] = __builtin_amdgcn_mfma_f32_16x16x32_bf16(aq[kf], bk, s[nf], 0, 0, 0);
      }

    const bool need_mask = (k0 + 63 > q0 + w * 16);
#pragma unroll
    for (int nf = 0; nf < 4; ++nf)
#pragma unroll
      for (int j = 0; j < 4; ++j) {
        float v = s[nf][j] * ATT_SCALE;
        if (need_mask) {
          int key = k0 + nf * 16 + l15;
          int qrow = q0 + w * 16 + l4 * 4 + j;
          if (key > qrow) v = -1.0e9f;
        }
        s[nf][j] = v;
      }

#pragma unroll
    for (int j = 0; j < 4; ++j) {
      float v = fmaxf(fmaxf(s[0][j], s[1][j]), fmaxf(s[2][j], s[3][j]));
      v = fmaxf(v, __shfl_xor(v, 1));
      v = fmaxf(v, __shfl_xor(v, 2));
      v = fmaxf(v, __shfl_xor(v, 4));
      v = fmaxf(v, __shfl_xor(v, 8));
      float mnew = fmaxf(mrun[j], v);
      float sc = __expf(mrun[j] - mnew);
      mrun[j] = mnew;
      float sum = 0.0f;
#pragma unroll
      for (int nf = 0; nf < 4; ++nf) {
        float p = __expf(s[nf][j] - mnew);
        s[nf][j] = p;
        sum += p;
      }
      sum += __shfl_xor(sum, 1);
      sum += __shfl_xor(sum, 2);
      sum += __shfl_xor(sum, 4);
      sum += __shfl_xor(sum, 8);
      lrun[j] = lrun[j] * sc + sum;
#pragma unroll
      for (int nd = 0; nd < 4; ++nd) acc[nd][j] *= sc;
    }

    // P -> LDS (per-wave region; within-wave ordering, no barrier needed)
#pragma unroll
    for (int nf = 0; nf < 4; ++nf)
#pragma unroll
      for (int j = 0; j < 4; ++j)
        Pl[(w * 16 + l4 * 4 + j) * 72 + nf * 16 + l15] = f2bf(s[nf][j]);

    bf16x8 ap[2];
#pragma unroll
    for (int kf = 0; kf < 2; ++kf)
      ap[kf] = *(const bf16x8*)&Pl[(w * 16 + l15) * 72 + kf * 32 + l4 * 8];
#pragma unroll
    for (int nd = 0; nd < 4; ++nd) {
      int dv = nd * 16 + l15;
      int xr = ((dv >> 3) & 7) << 3;
#pragma unroll
      for (int kf = 0; kf < 2; ++kf) {
        bf16x8 bvf = *(const bf16x8*)&Vt[dv * 72 + ((kf * 32 + l4 * 8) ^ xr)];
        acc[nd] = __builtin_amdgcn_mfma_f32_16x16x32_bf16(ap[kf], bvf, acc[nd], 0, 0, 0);
      }
    }
  };

  const int nkt = qt + 1;
  bf16x8 krA[2], vrA[2], krB[2], vrB[2];
  prefetch(0, krA, vrA);
  for (int kt = 0; kt < nkt;) {
    __syncthreads();
    stage_write(krA, vrA);
    if (kt + 1 < nkt) prefetch(kt + 1, krB, vrB);
    __syncthreads();
    compute(kt);
    ++kt;
    if (kt >= nkt) break;
    __syncthreads();
    stage_write(krB, vrB);
    if (kt + 1 < nkt) prefetch(kt + 1, krA, vrA);
    __syncthreads();
    compute(kt);
    ++kt;
  }

  // epilogue: reference reshape layout: flat = b*S*D + h*S*64 + s*64 + d
#pragma unroll
  for (int j = 0; j < 4; ++j) {
    float inv = 1.0f / lrun[j];
    int srow = q0 + w * 16 + l4 * 4 + j;
    size_t base = (size_t)b * SS * DD + (size_t)h * SS * 64 + (size_t)srow * 64;
#pragma unroll
    for (int nd = 0; nd < 4; ++nd)
      Xb[base + nd * 16 + l15] = f2bf(acc[nd][j] * inv);
  }
}

// ---------------------------------------------------------------- launch
extern "C" void kernel_launch(void* const* d_in, const int* in_sizes, int n_in,
                              void* d_out, int out_size, void* d_ws, size_t ws_size,
                              hipStream_t stream) {
  const float* q_in = (const float*)d_in[0];
  const float* k_in = (const float*)d_in[1];
  const float* v_in = (const float*)d_in[2];
  const float* Wq = (const float*)d_in[3];
  const float* bq = (const float*)d_in[4];
  const float* Wk = (const float*)d_in[5];
  const float* bk = (const float*)d_in[6];
  const float* Wv = (const float*)d_in[7];
  const float* bv = (const float*)d_in[8];
  const float* Wo = (const float*)d_in[9];
  const float* bo = (const float*)d_in[10];

  char* ws = (char*)d_ws;
  const size_t SZ_IN = (size_t)BB * SS * DD * 2;  // 8 MiB (bf16 activation)
  const size_t SZ_W = (size_t)DD * DD * 2;        // 2 MiB (bf16 weight)
  u16* qb  = (u16*)(ws);
  u16* kb  = (u16*)(ws + SZ_IN);
  u16* vb  = (u16*)(ws + 2 * SZ_IN);
  u16* wqb = (u16*)(ws + 3 * SZ_IN);
  u16* wkb = (u16*)(ws + 3 * SZ_IN + SZ_W);
  u16* wvb = (u16*)(ws + 3 * SZ_IN + 2 * SZ_W);
  u16* wob = (u16*)(ws + 3 * SZ_IN + 3 * SZ_W);
  u16* Qb  = (u16*)(ws + 3 * SZ_IN + 4 * SZ_W);
  u16* Kb  = (u16*)(ws + 4 * SZ_IN + 4 * SZ_W);
  u16* Vb  = (u16*)(ws + 5 * SZ_IN + 4 * SZ_W);
  u16* Xb  = (u16*)(ws + 6 * SZ_IN + 4 * SZ_W);

  // fp32 -> bf16
  cvt_bf16_kernel<<<dim3(2048, 3), 256, 0, stream>>>(q_in, k_in, v_in, nullptr,
                                                     qb, kb, vb, nullptr, (BB * SS * DD) / 4);
  cvt_bf16_kernel<<<dim3(1024, 4), 256, 0, stream>>>(Wq, Wk, Wv, Wo,
                                                     wqb, wkb, wvb, wob, (DD * DD) / 4);

  // Q/K/V projections, z-batched in one launch
  gemm_bt_kernel<0><<<dim3(32, 16, 3), 256, 0, stream>>>(
      qb, kb, vb, wqb, wkb, wvb, bq, bk, bv, Qb, Kb, Vb, BB * SS, DD, DD);

  // causal attention
  attn_kernel<<<dim3(SS / 64, BB * HH), 256, 0, stream>>>(Qb, Kb, Vb, Xb);

  // output projection (fp32 out)
  gemm_bt_kernel<1><<<dim3(32, 16, 1), 256, 0, stream>>>(
      Xb, Xb, Xb, wob, wob, wob, bo, bo, bo, d_out, d_out, d_out, BB * SS, DD, DD);
}